// Round 2
// baseline (146.938 us; speedup 1.0000x reference)
//
#include <hip/hip_runtime.h>
#include <cstdint>
#include <cstddef>

typedef unsigned short u16;
typedef unsigned int   u32;
typedef __attribute__((ext_vector_type(4))) float f32x4;
typedef __attribute__((ext_vector_type(8))) short bf16x8;
typedef __attribute__((ext_vector_type(4))) unsigned short u16x4;
typedef __attribute__((ext_vector_type(2))) u32 u32x2;
typedef __attribute__((ext_vector_type(4))) u32 u32x4;

#define DEVI static __device__ __forceinline__
#define MFMA16(a,b,c) __builtin_amdgcn_mfma_f32_16x16x32_bf16((a),(b),(c),0,0,0)

// f32 -> bf16 bits, round-to-nearest-even
DEVI u16 f2b(float f) {
  u32 u = __builtin_bit_cast(u32, f);
  u32 r = u + 0x7fffu + ((u >> 16) & 1u);
  return (u16)(r >> 16);
}

DEVI void load_lds16(const void* g, void* l) {
  __builtin_amdgcn_global_load_lds(
      (const __attribute__((address_space(1))) u32*)g,
      (__attribute__((address_space(3))) u32*)l, 16, 0, 0);
}

DEVI int perm_o(int o) { return 4 * (o & 63) + (o >> 6); }   // o' = h*64+i -> o = 4i+h
DEVI int swzb(int byteoff, int row) { return byteoff ^ ((row & 7) << 4); }

// ---------------------------------------------------------------- weights prep
__global__ __launch_bounds__(256) void k_prep_w(
    const float* __restrict__ wq, const float* __restrict__ wk,
    const float* __restrict__ wv, const float* __restrict__ wm,
    const float* __restrict__ bq, const float* __restrict__ bk, const float* __restrict__ bv,
    u16* __restrict__ WQ, u16* __restrict__ WK, u16* __restrict__ WV, u16* __restrict__ WM,
    float* __restrict__ BQ, float* __restrict__ BK, float* __restrict__ BV)
{
  int row = blockIdx.x, t = threadIdx.x, m = blockIdx.y;
  if (m == 0)      WQ[row * 256 + t] = f2b(wq[perm_o(row) * 256 + t]);
  else if (m == 1) WK[row * 256 + t] = f2b(wk[perm_o(row) * 256 + t]);
  else if (m == 2) WV[row * 256 + t] = f2b(wv[perm_o(row) * 256 + t]);
  else if (m == 3) WM[row * 256 + t] = f2b(wm[row * 256 + perm_o(t)]);
  else if (row == 0) {
    BQ[t] = bq[perm_o(t)];
    BK[t] = bk[perm_o(t)];
    BV[t] = bv[perm_o(t)];
  }
}

// ---------------------------------------------- transpose+convert: [b][c][n]f32 -> [b][n][c]bf16
__global__ __launch_bounds__(256) void k_transpose(
    const float* __restrict__ q, const float* __restrict__ k, const float* __restrict__ v,
    u16* __restrict__ xq, u16* __restrict__ xk, u16* __restrict__ xv)
{
  __shared__ u16 tile[64][68];   // [c][n], padded
  const int N = 2048, D = 256;
  int n0 = blockIdx.x * 64, c0 = blockIdx.y * 64;
  int b = blockIdx.z & 7, which = blockIdx.z >> 3;
  const float* src = (which == 0 ? q : which == 1 ? k : v) + (size_t)b * D * N;
  u16* dst = (which == 0 ? xq : which == 1 ? xk : xv) + (size_t)b * N * D;
  int t = threadIdx.x;
  int cl = t >> 4, ng = t & 15;
#pragma unroll
  for (int cc = 0; cc < 4; ++cc) {
    int c = cl + 16 * cc;
    f32x4 val = *(const f32x4*)&src[(size_t)(c0 + c) * N + n0 + ng * 4];
#pragma unroll
    for (int j = 0; j < 4; ++j) tile[c][ng * 4 + j] = f2b(val[j]);
  }
  __syncthreads();
  int n = t & 63, cq = t >> 6;
  union { u16 s[16]; u32x4 v4[2]; } pk;
#pragma unroll
  for (int j = 0; j < 16; ++j) pk.s[j] = tile[cq * 16 + j][n];
  u32x4* o = (u32x4*)&dst[(size_t)(n0 + n) * D + c0 + cq * 16];
  o[0] = pk.v4[0];
  o[1] = pk.v4[1];
}

// ---------------------------------------------------------------- GEMM: C = A[M,256] * B[N',256]^T
// EPI 0: Q/K-proj  -> bf16 [b][h][n][i]   (rows = n, cols = o' = h*64+i), bias[col]
// EPI 1: V-proj    -> bf16 [b][row][col]  (rows = o', cols = n), bias[row]
// EPI 2: M-proj    -> f32  [b][row][col]  + bias[row]
template<int EPI>
__global__ __launch_bounds__(256) void k_gemm(
    const u16* __restrict__ A, long sA,
    const u16* __restrict__ Bm, long sB,
    const float* __restrict__ bias,
    void* __restrict__ out, long sOut)
{
  __shared__ u16 lA[128 * 64];
  __shared__ u16 lB[128 * 64];
  int t = threadIdx.x, b = blockIdx.z;
  const u16* Ab = A + (size_t)b * sA + (size_t)blockIdx.x * 128 * 256;
  const u16* Bb = Bm + (size_t)b * sB + (size_t)blockIdx.y * 128 * 256;
  int l = t & 63, w = t >> 6, g = l >> 4, col = l & 15;
  int wr = w >> 1, wc = w & 1;
  f32x4 acc[4][4] = {};
  for (int k0 = 0; k0 < 256; k0 += 64) {
    __syncthreads();
#pragma unroll
    for (int s = 0; s < 4; ++s) {
      int slot = t + 256 * s;
      int r = slot >> 3, ch = slot & 7;
      load_lds16(Ab + (size_t)r * 256 + k0 + ch * 8, (char*)lA + slot * 16);
      load_lds16(Bb + (size_t)r * 256 + k0 + ch * 8, (char*)lB + slot * 16);
    }
    asm volatile("s_waitcnt vmcnt(0)" ::: "memory");
    __syncthreads();
#pragma unroll
    for (int kc = 0; kc < 2; ++kc) {
      bf16x8 af[4], bfr[4];
#pragma unroll
      for (int mt = 0; mt < 4; ++mt)
        af[mt] = *(const bf16x8*)&lA[(wr * 64 + mt * 16 + col) * 64 + kc * 32 + g * 8];
#pragma unroll
      for (int nt = 0; nt < 4; ++nt)
        bfr[nt] = *(const bf16x8*)&lB[(wc * 64 + nt * 16 + col) * 64 + kc * 32 + g * 8];
#pragma unroll
      for (int mt = 0; mt < 4; ++mt)
#pragma unroll
        for (int nt = 0; nt < 4; ++nt)
          acc[mt][nt] = MFMA16(af[mt], bfr[nt], acc[mt][nt]);
    }
  }
  if (EPI == 0) {
    u16* o = (u16*)out + (size_t)b * sOut;
#pragma unroll
    for (int nt = 0; nt < 4; ++nt) {
      int op = blockIdx.y * 128 + wc * 64 + nt * 16 + col;
      int hh = op >> 6, ii = op & 63;
      float bv = bias[op];
#pragma unroll
      for (int mt = 0; mt < 4; ++mt) {
        int nbase = blockIdx.x * 128 + wr * 64 + mt * 16 + g * 4;
#pragma unroll
        for (int r = 0; r < 4; ++r)
          o[((size_t)(hh * 2048 + nbase + r)) * 64 + ii] = f2b(acc[mt][nt][r] + bv);
      }
    }
  } else if (EPI == 1) {
    u16* o = (u16*)out + (size_t)b * sOut;
#pragma unroll
    for (int mt = 0; mt < 4; ++mt)
#pragma unroll
      for (int r = 0; r < 4; ++r) {
        int row = blockIdx.x * 128 + wr * 64 + mt * 16 + g * 4 + r;
        float bv = bias[row];
#pragma unroll
        for (int nt = 0; nt < 4; ++nt) {
          int cn = blockIdx.y * 128 + wc * 64 + nt * 16 + col;
          o[(size_t)row * 2048 + cn] = f2b(acc[mt][nt][r] + bv);
        }
      }
  } else {
    float* o = (float*)out + (size_t)b * sOut;
#pragma unroll
    for (int mt = 0; mt < 4; ++mt)
#pragma unroll
      for (int r = 0; r < 4; ++r) {
        int row = blockIdx.x * 128 + wr * 64 + mt * 16 + g * 4 + r;
        float bv = bias[row];
#pragma unroll
        for (int nt = 0; nt < 4; ++nt) {
          int cn = blockIdx.y * 128 + wc * 64 + nt * 16 + col;
          o[(size_t)row * 2048 + cn] = acc[mt][nt][r] + bv;
        }
      }
  }
}

// ---------------------------------------------------------------- flash attention
// Qt,Kt: [b][h][n][64] bf16 ; Vw: [b][o'=h*64+i][n] bf16 ; Xws: [b][n][c'=h*64+i] bf16
// 2-phase prefetch double-buffer; softmax in exp2 domain; defer-max (THR=8);
// cvt_pk_bf16_f32 for P conversion; setprio around MFMA clusters.
__global__ __launch_bounds__(256) void k_attn(
    const u16* __restrict__ Qt, const u16* __restrict__ Kt,
    const u16* __restrict__ Vw, u16* __restrict__ Xws)
{
  __shared__ u16 lK[2][64 * 64];     // [m][i], XOR-swizzled content
  __shared__ u16 lV[2][64 * 64];     // [i][m], XOR-swizzled content
  __shared__ u16 lP[4][16 * 72];     // per-wave [n][m], padded to 72
  const float SC2 = 0.18033688011112042f;  // 0.125 * log2(e)
  int t = threadIdx.x, l = t & 63, w = t >> 6, g = l >> 4, col = l & 15;
  int nb = blockIdx.x, hh = blockIdx.y, b = blockIdx.z;
  const u16* Qb = Qt + ((size_t)(b * 4 + hh) * 2048) * 64;
  const u16* Kb = Kt + ((size_t)(b * 4 + hh) * 2048) * 64;
  const u16* Vb = Vw + ((size_t)(b * 256 + hh * 64)) * 2048;
  int nq = nb * 64 + w * 16 + col;
  bf16x8 qf0 = *(const bf16x8*)&Qb[(size_t)nq * 64 + g * 8];
  bf16x8 qf1 = *(const bf16x8*)&Qb[(size_t)nq * 64 + 32 + g * 8];
  f32x4 xacc[4] = {};
  float m_run = -1e30f, l_run = 0.f;

  // ---- staging helpers (pre-swizzled global source, linear LDS dest) ----
  auto stageK = [&](int d, int m0) {
    const char* ktile = (const char*)(Kb + (size_t)m0 * 64);
#pragma unroll
    for (int ss = 0; ss < 2; ++ss) {
      int s = t + 256 * ss;
      int boff = (s * 16) ^ (((s >> 3) & 7) << 4);
      load_lds16(ktile + boff, (char*)&lK[d][0] + s * 16);
    }
  };
  auto stageV = [&](int d, int m0) {
#pragma unroll
    for (int ss = 0; ss < 2; ++ss) {
      int s = t + 256 * ss;
      int i = s >> 3, ch = s & 7;
      const char* vsrc = (const char*)(Vb + (size_t)i * 2048 + m0) + ((ch ^ (i & 7)) << 4);
      load_lds16(vsrc, (char*)&lV[d][0] + s * 16);
    }
  };

  stageK(0, 0);
  stageV(0, 0);
  asm volatile("s_waitcnt vmcnt(0)" ::: "memory");
  __syncthreads();

  for (int it = 0; it < 32; ++it) {
    int cur = it & 1;
    if (it < 31) {                       // prefetch next tile into other buffer
      stageK(cur ^ 1, (it + 1) * 64);
      stageV(cur ^ 1, (it + 1) * 64);
    }
    const u16* Kbuf = lK[cur];
    const u16* Vbuf = lV[cur];

    // S^T[m][n] = sum_i K[m][i] * Q[n][i]
    f32x4 sacc[4] = {};
    __builtin_amdgcn_s_setprio(1);
#pragma unroll
    for (int kc = 0; kc < 2; ++kc) {
      bf16x8 qf = kc ? qf1 : qf0;
#pragma unroll
      for (int mt = 0; mt < 4; ++mt) {
        int row = mt * 16 + col;
        bf16x8 kf = *(const bf16x8*)((const char*)Kbuf + swzb(row * 128 + kc * 64 + g * 16, row));
        sacc[mt] = MFMA16(kf, qf, sacc[mt]);
      }
    }
    __builtin_amdgcn_s_setprio(0);

    // online softmax over m (rows); this lane's column n = col
    float a0 = fmaxf(fmaxf(sacc[0][0], sacc[0][1]), fmaxf(sacc[0][2], sacc[0][3]));
    float a1 = fmaxf(fmaxf(sacc[1][0], sacc[1][1]), fmaxf(sacc[1][2], sacc[1][3]));
    float a2 = fmaxf(fmaxf(sacc[2][0], sacc[2][1]), fmaxf(sacc[2][2], sacc[2][3]));
    float a3 = fmaxf(fmaxf(sacc[3][0], sacc[3][1]), fmaxf(sacc[3][2], sacc[3][3]));
    float pmax = fmaxf(fmaxf(a0, a1), fmaxf(a2, a3));
    pmax = fmaxf(pmax, __shfl_xor(pmax, 16));
    pmax = fmaxf(pmax, __shfl_xor(pmax, 32));
    float m2c = pmax * SC2;
    if (__any(m2c > m_run + 8.0f)) {     // defer-max: rescale only on real growth
      float mnew = fmaxf(m_run, m2c);
      float fs = __builtin_amdgcn_exp2f(m_run - mnew);
      l_run *= fs;
#pragma unroll
      for (int i = 0; i < 4; ++i) xacc[i] *= fs;
      m_run = mnew;
    }
    float psum = 0.f;
    u16* prow = &lP[w][col * 72];
#pragma unroll
    for (int mt = 0; mt < 4; ++mt) {
      float p0 = __builtin_amdgcn_exp2f(__builtin_fmaf(sacc[mt][0], SC2, -m_run));
      float p1 = __builtin_amdgcn_exp2f(__builtin_fmaf(sacc[mt][1], SC2, -m_run));
      float p2 = __builtin_amdgcn_exp2f(__builtin_fmaf(sacc[mt][2], SC2, -m_run));
      float p3 = __builtin_amdgcn_exp2f(__builtin_fmaf(sacc[mt][3], SC2, -m_run));
      psum += (p0 + p1) + (p2 + p3);
      u32 pkA, pkB;
      asm("v_cvt_pk_bf16_f32 %0, %1, %2" : "=v"(pkA) : "v"(p0), "v"(p1));
      asm("v_cvt_pk_bf16_f32 %0, %1, %2" : "=v"(pkB) : "v"(p2), "v"(p3));
      u32x2 w2; w2[0] = pkA; w2[1] = pkB;
      *(u32x2*)((char*)prow + mt * 32 + g * 8) = w2;
    }
    psum += __shfl_xor(psum, 16);
    psum += __shfl_xor(psum, 32);
    l_run += psum;

    asm volatile("s_waitcnt lgkmcnt(0)" ::: "memory");
    __builtin_amdgcn_sched_barrier(0);
    // x^T[i][n] += sum_m V^T[i][m] * P[n][m]
    __builtin_amdgcn_s_setprio(1);
#pragma unroll
    for (int kc = 0; kc < 2; ++kc) {
      bf16x8 pf = *(const bf16x8*)&lP[w][col * 72 + kc * 32 + g * 8];
#pragma unroll
      for (int itn = 0; itn < 4; ++itn) {
        int row = itn * 16 + col;
        bf16x8 vf = *(const bf16x8*)((const char*)Vbuf + swzb(row * 128 + kc * 64 + g * 16, row));
        xacc[itn] = MFMA16(vf, pf, xacc[itn]);
      }
    }
    __builtin_amdgcn_s_setprio(0);

    asm volatile("s_waitcnt vmcnt(0)" ::: "memory");   // prefetch done (hidden under compute)
    __syncthreads();
  }

  float inv = 1.0f / l_run;
  u16* Ob = Xws + (size_t)b * 2048 * 256;
#pragma unroll
  for (int itn = 0; itn < 4; ++itn) {
    u16x4 vv;
#pragma unroll
    for (int r = 0; r < 4; ++r) vv[r] = f2b(xacc[itn][r] * inv);
    *(u16x4*)&Ob[(size_t)nq * 256 + hh * 64 + itn * 16 + g * 4] = vv;
  }
}

// ---------------------------------------------------------------- launch
extern "C" void kernel_launch(void* const* d_in, const int* in_sizes, int n_in,
                              void* d_out, int out_size, void* d_ws, size_t ws_size,
                              hipStream_t stream)
{
  const float* q_in = (const float*)d_in[0];
  const float* k_in = (const float*)d_in[1];
  const float* v_in = (const float*)d_in[2];
  const float* w_q  = (const float*)d_in[3];
  const float* b_q  = (const float*)d_in[4];
  const float* w_k  = (const float*)d_in[5];
  const float* b_k  = (const float*)d_in[6];
  const float* w_v  = (const float*)d_in[7];
  const float* b_v  = (const float*)d_in[8];
  const float* w_m  = (const float*)d_in[9];
  const float* b_m  = (const float*)d_in[10];

  char* ws = (char*)d_ws;
  u16* XT_Q = (u16*)(ws + 0);           // [8][2048][256] bf16; reused as XWS after Q-proj
  u16* XT_K = (u16*)(ws + 8388608);
  u16* XT_V = (u16*)(ws + 16777216);
  u16* QT   = (u16*)(ws + 25165824);    // [8][4][2048][64]
  u16* KT   = (u16*)(ws + 33554432);
  u16* VW   = (u16*)(ws + 41943040);    // [8][256][2048]
  u16* WQ   = (u16*)(ws + 50331648);
  u16* WK   = (u16*)(ws + 50462720);
  u16* WV   = (u16*)(ws + 50593792);
  u16* WM   = (u16*)(ws + 50724864);
  float* BQ = (float*)(ws + 50855936);
  float* BK = (float*)(ws + 50856960);
  float* BV = (float*)(ws + 50857984);

  k_prep_w<<<dim3(256, 5), 256, 0, stream>>>(w_q, w_k, w_v, w_m, b_q, b_k, b_v,
                                             WQ, WK, WV, WM, BQ, BK, BV);
  k_transpose<<<dim3(32, 4, 24), 256, 0, stream>>>(q_in, k_in, v_in, XT_Q, XT_K, XT_V);
  k_gemm<0><<<dim3(16, 2, 8), 256, 0, stream>>>(XT_Q, 2048L * 256, WQ, 0, BQ, QT, 4L * 2048 * 64);
  k_gemm<0><<<dim3(16, 2, 8), 256, 0, stream>>>(XT_K, 2048L * 256, WK, 0, BK, KT, 4L * 2048 * 64);
  k_gemm<1><<<dim3(2, 16, 8), 256, 0, stream>>>(WV, 0, XT_V, 2048L * 256, BV, VW, 256L * 2048);
  k_attn<<<dim3(32, 4, 8), 256, 0, stream>>>(QT, KT, VW, XT_Q);
  k_gemm<2><<<dim3(2, 16, 8), 256, 0, stream>>>(WM, 0, XT_Q, 2048L * 256, b_m, d_out, 256L * 2048);
}

// Round 3
// 121.138 us; speedup vs baseline: 1.2130x; 1.2130x over previous
//
#include <hip/hip_runtime.h>
#include <cstdint>
#include <cstddef>

typedef unsigned short u16;
typedef unsigned int   u32;
typedef __attribute__((ext_vector_type(4))) float f32x4;
typedef __attribute__((ext_vector_type(8))) short bf16x8;
typedef __attribute__((ext_vector_type(4))) unsigned short u16x4;
typedef __attribute__((ext_vector_type(2))) u32 u32x2;
typedef __attribute__((ext_vector_type(4))) u32 u32x4;

#define DEVI static __device__ __forceinline__
#define MFMA16(a,b,c) __builtin_amdgcn_mfma_f32_16x16x32_bf16((a),(b),(c),0,0,0)

// f32 -> bf16 bits, round-to-nearest-even
DEVI u16 f2b(float f) {
  u32 u = __builtin_bit_cast(u32, f);
  u32 r = u + 0x7fffu + ((u >> 16) & 1u);
  return (u16)(r >> 16);
}

DEVI void load_lds16(const void* g, void* l) {
  __builtin_amdgcn_global_load_lds(
      (const __attribute__((address_space(1))) u32*)g,
      (__attribute__((address_space(3))) u32*)l, 16, 0, 0);
}

DEVI int perm_o(int o) { return 4 * (o & 63) + (o >> 6); }   // o' = h*64+i -> o = 4i+h

// ---------------------------------------------------------------- weights prep
__global__ __launch_bounds__(256) void k_prep_w(
    const float* __restrict__ wq, const float* __restrict__ wk,
    const float* __restrict__ wv, const float* __restrict__ wm,
    const float* __restrict__ bq, const float* __restrict__ bk, const float* __restrict__ bv,
    u16* __restrict__ WQ, u16* __restrict__ WK, u16* __restrict__ WV, u16* __restrict__ WM,
    float* __restrict__ BQ, float* __restrict__ BK, float* __restrict__ BV)
{
  int row = blockIdx.x, t = threadIdx.x, m = blockIdx.y;
  if (m == 0)      WQ[row * 256 + t] = f2b(wq[perm_o(row) * 256 + t]);
  else if (m == 1) WK[row * 256 + t] = f2b(wk[perm_o(row) * 256 + t]);
  else if (m == 2) WV[row * 256 + t] = f2b(wv[perm_o(row) * 256 + t]);
  else if (m == 3) WM[row * 256 + t] = f2b(wm[row * 256 + perm_o(t)]);
  else if (row == 0) {
    BQ[t] = bq[perm_o(t)];
    BK[t] = bk[perm_o(t)];
    BV[t] = bv[perm_o(t)];
  }
}

// ---------------------------------------------- transpose+convert: [b][c][n]f32 -> [b][n][c]bf16
__global__ __launch_bounds__(256) void k_transpose(
    const float* __restrict__ q, const float* __restrict__ k, const float* __restrict__ v,
    u16* __restrict__ xq, u16* __restrict__ xk, u16* __restrict__ xv)
{
  __shared__ u16 tile[64][68];   // [c][n], padded
  const int N = 2048, D = 256;
  int n0 = blockIdx.x * 64, c0 = blockIdx.y * 64;
  int b = blockIdx.z & 7, which = blockIdx.z >> 3;
  const float* src = (which == 0 ? q : which == 1 ? k : v) + (size_t)b * D * N;
  u16* dst = (which == 0 ? xq : which == 1 ? xk : xv) + (size_t)b * N * D;
  int t = threadIdx.x;
  int cl = t >> 4, ng = t & 15;
#pragma unroll
  for (int cc = 0; cc < 4; ++cc) {
    int c = cl + 16 * cc;
    f32x4 val = *(const f32x4*)&src[(size_t)(c0 + c) * N + n0 + ng * 4];
#pragma unroll
    for (int j = 0; j < 4; ++j) tile[c][ng * 4 + j] = f2b(val[j]);
  }
  __syncthreads();
  int n = t & 63, cq = t >> 6;
  union { u16 s[16]; u32x4 v4[2]; } pk;
#pragma unroll
  for (int j = 0; j < 16; ++j) pk.s[j] = tile[cq * 16 + j][n];
  u32x4* o = (u32x4*)&dst[(size_t)(n0 + n) * D + c0 + cq * 16];
  o[0] = pk.v4[0];
  o[1] = pk.v4[1];
}

// ---------------------------------------------------------------- GEMM: C = A[M,256] * B[N',256]^T
// EPI 0: Q/K-proj  -> bf16 [b][h][n][i]   (rows = n, cols = o' = h*64+i), bias[col]
// EPI 1: V-proj    -> bf16 [b][row][col]  (rows = o', cols = n), bias[row]
// EPI 2: M-proj    -> f32  [b][row][col]  + bias[row]
template<int EPI>
__global__ __launch_bounds__(256) void k_gemm(
    const u16* __restrict__ A, long sA,
    const u16* __restrict__ Bm, long sB,
    const float* __restrict__ bias,
    void* __restrict__ out, long sOut)
{
  __shared__ u16 lA[128 * 64];
  __shared__ u16 lB[128 * 64];
  int t = threadIdx.x, b = blockIdx.z;
  const u16* Ab = A + (size_t)b * sA + (size_t)blockIdx.x * 128 * 256;
  const u16* Bb = Bm + (size_t)b * sB + (size_t)blockIdx.y * 128 * 256;
  int l = t & 63, w = t >> 6, g = l >> 4, col = l & 15;
  int wr = w >> 1, wc = w & 1;
  f32x4 acc[4][4] = {};
  for (int k0 = 0; k0 < 256; k0 += 64) {
    __syncthreads();
#pragma unroll
    for (int s = 0; s < 4; ++s) {
      int slot = t + 256 * s;
      int r = slot >> 3, ch = slot & 7;
      load_lds16(Ab + (size_t)r * 256 + k0 + ch * 8, (char*)lA + slot * 16);
      load_lds16(Bb + (size_t)r * 256 + k0 + ch * 8, (char*)lB + slot * 16);
    }
    asm volatile("s_waitcnt vmcnt(0)" ::: "memory");
    __syncthreads();
#pragma unroll
    for (int kc = 0; kc < 2; ++kc) {
      bf16x8 af[4], bfr[4];
#pragma unroll
      for (int mt = 0; mt < 4; ++mt)
        af[mt] = *(const bf16x8*)&lA[(wr * 64 + mt * 16 + col) * 64 + kc * 32 + g * 8];
#pragma unroll
      for (int nt = 0; nt < 4; ++nt)
        bfr[nt] = *(const bf16x8*)&lB[(wc * 64 + nt * 16 + col) * 64 + kc * 32 + g * 8];
#pragma unroll
      for (int mt = 0; mt < 4; ++mt)
#pragma unroll
        for (int nt = 0; nt < 4; ++nt)
          acc[mt][nt] = MFMA16(af[mt], bfr[nt], acc[mt][nt]);
    }
  }
  if (EPI == 0) {
    u16* o = (u16*)out + (size_t)b * sOut;
#pragma unroll
    for (int nt = 0; nt < 4; ++nt) {
      int op = blockIdx.y * 128 + wc * 64 + nt * 16 + col;
      int hh = op >> 6, ii = op & 63;
      float bv = bias[op];
#pragma unroll
      for (int mt = 0; mt < 4; ++mt) {
        int nbase = blockIdx.x * 128 + wr * 64 + mt * 16 + g * 4;
#pragma unroll
        for (int r = 0; r < 4; ++r)
          o[((size_t)(hh * 2048 + nbase + r)) * 64 + ii] = f2b(acc[mt][nt][r] + bv);
      }
    }
  } else if (EPI == 1) {
    u16* o = (u16*)out + (size_t)b * sOut;
#pragma unroll
    for (int mt = 0; mt < 4; ++mt)
#pragma unroll
      for (int r = 0; r < 4; ++r) {
        int row = blockIdx.x * 128 + wr * 64 + mt * 16 + g * 4 + r;
        float bv = bias[row];
#pragma unroll
        for (int nt = 0; nt < 4; ++nt) {
          int cn = blockIdx.y * 128 + wc * 64 + nt * 16 + col;
          o[(size_t)row * 2048 + cn] = f2b(acc[mt][nt][r] + bv);
        }
      }
  } else {
    float* o = (float*)out + (size_t)b * sOut;
#pragma unroll
    for (int mt = 0; mt < 4; ++mt)
#pragma unroll
      for (int r = 0; r < 4; ++r) {
        int row = blockIdx.x * 128 + wr * 64 + mt * 16 + g * 4 + r;
        float bv = bias[row];
#pragma unroll
        for (int nt = 0; nt < 4; ++nt) {
          int cn = blockIdx.y * 128 + wc * 64 + nt * 16 + col;
          o[(size_t)row * 2048 + cn] = acc[mt][nt][r] + bv;
        }
      }
  }
}

// ---------------------------------------------------------------- flash attention
// Qt,Kt: [b][h][n][64] bf16 ; Vw: [b][o'=h*64+i][n] bf16 ; Xws: [b][n][c'=h*64+i] bf16
// Single-buffer r1 structure + VALU diet:
//   max-free streaming softmax (ratchet rescale on xsum overflow check),
//   Sum(p) via ones-MFMA accumulated into xsum (rescales with xacc),
//   cvt_pk_bf16_f32 P conversion, hoisted lane-constant addressing, setprio.
__global__ __launch_bounds__(256) void k_attn(
    const u16* __restrict__ Qt, const u16* __restrict__ Kt,
    const u16* __restrict__ Vw, u16* __restrict__ Xws)
{
  __shared__ u16 lK[64 * 64];        // [m][i], XOR-swizzled content
  __shared__ u16 lV[64 * 64];        // [i][m], XOR-swizzled content
  __shared__ u16 lP[4][16 * 72];     // per-wave [n][m], padded to 72 (16B-aligned rows)
  const float SC2 = 0.18033688011112042f;  // 0.125 * log2(e)
  int t = threadIdx.x, l = t & 63, w = t >> 6, g = l >> 4, col = l & 15;
  int nb = blockIdx.x, hh = blockIdx.y, b = blockIdx.z;
  const u16* Qb = Qt + ((size_t)(b * 4 + hh) * 2048) * 64;
  const u16* Kb = Kt + ((size_t)(b * 4 + hh) * 2048) * 64;
  const u16* Vb = Vw + ((size_t)(b * 256 + hh * 64)) * 2048;
  int nq = nb * 64 + w * 16 + col;
  bf16x8 qf0 = *(const bf16x8*)&Qb[(size_t)nq * 64 + g * 8];
  bf16x8 qf1 = *(const bf16x8*)&Qb[(size_t)nq * 64 + 32 + g * 8];

  // ---- hoisted lane-constant offsets ----
  int s0 = t, s1 = t + 256;
  u32 kOff0 = (u32)((s0 * 16) ^ (((s0 >> 3) & 7) << 4));
  u32 kOff1 = (u32)((s1 * 16) ^ (((s1 >> 3) & 7) << 4));
  u32 vOff0 = (u32)(((s0 >> 3) << 12) + ((((s0 & 7) ^ ((s0 >> 3) & 7))) << 4));
  u32 vOff1 = (u32)(((s1 >> 3) << 12) + ((((s1 & 7) ^ ((s1 >> 3) & 7))) << 4));
  // frag read offsets: chunk idx c = kc*4+g, row = mt*16+col, XOR over (c ^ (col&7))
  u32 a0 = (u32)(col * 128 + (((0 + g) ^ (col & 7)) << 4));   // kc = 0
  u32 a1 = (u32)(col * 128 + (((4 + g) ^ (col & 7)) << 4));   // kc = 1
  u32 pR = (u32)(w * 2304 + col * 144 + g * 16);              // P read base
  u32 pW = (u32)(w * 2304 + col * 144 + g * 8);               // P write base

  bf16x8 ones;
  { union { u32 u[4]; bf16x8 v; } o; o.u[0] = o.u[1] = o.u[2] = o.u[3] = 0x3F803F80u; ones = o.v; }

  f32x4 xacc[4] = {};
  f32x4 xsum = {};
  float m_run = 0.0f;

  for (int it = 0; it < 32; ++it) {
    __syncthreads();                               // all waves done reading prev K/V
    const char* kb = (const char*)Kb + (size_t)it * 8192;
    const char* vb = (const char*)Vb + (size_t)it * 128;
    load_lds16(kb + kOff0, (char*)lK + s0 * 16);
    load_lds16(kb + kOff1, (char*)lK + s1 * 16);
    load_lds16(vb + vOff0, (char*)lV + s0 * 16);
    load_lds16(vb + vOff1, (char*)lV + s1 * 16);

    // ratchet rescale (rare) — overlaps the staging latency
    if (__any(xsum[0] > 16777216.0f)) {            // 2^24
      const float ds = 5.9604644775390625e-8f;     // 2^-24
#pragma unroll
      for (int mt = 0; mt < 4; ++mt) xacc[mt] *= ds;
      xsum *= ds;
      m_run += 24.0f;
    }

    asm volatile("s_waitcnt vmcnt(0)" ::: "memory");
    __syncthreads();

    // S^T[m][n] = sum_i K[m][i] * Q[n][i]
    f32x4 sacc[4] = {};
    __builtin_amdgcn_s_setprio(1);
#pragma unroll
    for (int mt = 0; mt < 4; ++mt) {
      bf16x8 kf = *(const bf16x8*)((const char*)lK + (a0 + (u32)(mt * 2048)));
      sacc[mt] = MFMA16(kf, qf0, sacc[mt]);
    }
#pragma unroll
    for (int mt = 0; mt < 4; ++mt) {
      bf16x8 kf = *(const bf16x8*)((const char*)lK + (a1 + (u32)(mt * 2048)));
      sacc[mt] = MFMA16(kf, qf1, sacc[mt]);
    }
    __builtin_amdgcn_s_setprio(0);

    // p = exp2(s*SC2 - m_run), packed to bf16, written to per-wave P strip
#pragma unroll
    for (int mt = 0; mt < 4; ++mt) {
      float p0 = __builtin_amdgcn_exp2f(__builtin_fmaf(sacc[mt][0], SC2, -m_run));
      float p1 = __builtin_amdgcn_exp2f(__builtin_fmaf(sacc[mt][1], SC2, -m_run));
      float p2 = __builtin_amdgcn_exp2f(__builtin_fmaf(sacc[mt][2], SC2, -m_run));
      float p3 = __builtin_amdgcn_exp2f(__builtin_fmaf(sacc[mt][3], SC2, -m_run));
      u32 pkA, pkB;
      asm("v_cvt_pk_bf16_f32 %0, %1, %2" : "=v"(pkA) : "v"(p0), "v"(p1));
      asm("v_cvt_pk_bf16_f32 %0, %1, %2" : "=v"(pkB) : "v"(p2), "v"(p3));
      u32x2 w2; w2[0] = pkA; w2[1] = pkB;
      *(u32x2*)((char*)lP + (pW + (u32)(mt * 32))) = w2;
    }

    // x^T[i][n] += sum_m V^T[i][m] * P[n][m]; xsum += sum_m P[n][m] (ones-MFMA)
    __builtin_amdgcn_s_setprio(1);
#pragma unroll
    for (int kc = 0; kc < 2; ++kc) {
      bf16x8 pf = *(const bf16x8*)((const char*)lP + (pR + (u32)(kc * 64)));
      xsum = MFMA16(ones, pf, xsum);
      u32 aa = kc ? a1 : a0;
#pragma unroll
      for (int mt = 0; mt < 4; ++mt) {
        bf16x8 vf = *(const bf16x8*)((const char*)lV + (aa + (u32)(mt * 2048)));
        xacc[mt] = MFMA16(vf, pf, xacc[mt]);
      }
    }
    __builtin_amdgcn_s_setprio(0);
  }

  float inv = 1.0f / xsum[0];
  u16* Ob = Xws + (size_t)b * 2048 * 256;
#pragma unroll
  for (int itn = 0; itn < 4; ++itn) {
    u16x4 vv;
#pragma unroll
    for (int r = 0; r < 4; ++r) vv[r] = f2b(xacc[itn][r] * inv);
    *(u16x4*)&Ob[(size_t)nq * 256 + hh * 64 + itn * 16 + g * 4] = vv;
  }
}

// ---------------------------------------------------------------- launch
extern "C" void kernel_launch(void* const* d_in, const int* in_sizes, int n_in,
                              void* d_out, int out_size, void* d_ws, size_t ws_size,
                              hipStream_t stream)
{
  const float* q_in = (const float*)d_in[0];
  const float* k_in = (const float*)d_in[1];
  const float* v_in = (const float*)d_in[2];
  const float* w_q  = (const float*)d_in[3];
  const float* b_q  = (const float*)d_in[4];
  const float* w_k  = (const float*)d_in[5];
  const float* b_k  = (const float*)d_in[6];
  const float* w_v  = (const float*)d_in[7];
  const float* b_v  = (const float*)d_in[8];
  const float* w_m  = (const float*)d_in[9];
  const float* b_m  = (const float*)d_in[10];

  char* ws = (char*)d_ws;
  u16* XT_Q = (u16*)(ws + 0);           // [8][2048][256] bf16; reused as XWS after Q-proj
  u16* XT_K = (u16*)(ws + 8388608);
  u16* XT_V = (u16*)(ws + 16777216);
  u16* QT   = (u16*)(ws + 25165824);    // [8][4][2048][64]
  u16* KT   = (u16*)(ws + 33554432);
  u16* VW   = (u16*)(ws + 41943040);    // [8][256][2048]
  u16* WQ   = (u16*)(ws + 50331648);
  u16* WK   = (u16*)(ws + 50462720);
  u16* WV   = (u16*)(ws + 50593792);
  u16* WM   = (u16*)(ws + 50724864);
  float* BQ = (float*)(ws + 50855936);
  float* BK = (float*)(ws + 50856960);
  float* BV = (float*)(ws + 50857984);

  k_prep_w<<<dim3(256, 5), 256, 0, stream>>>(w_q, w_k, w_v, w_m, b_q, b_k, b_v,
                                             WQ, WK, WV, WM, BQ, BK, BV);
  k_transpose<<<dim3(32, 4, 24), 256, 0, stream>>>(q_in, k_in, v_in, XT_Q, XT_K, XT_V);
  k_gemm<0><<<dim3(16, 2, 8), 256, 0, stream>>>(XT_Q, 2048L * 256, WQ, 0, BQ, QT, 4L * 2048 * 64);
  k_gemm<0><<<dim3(16, 2, 8), 256, 0, stream>>>(XT_K, 2048L * 256, WK, 0, BK, KT, 4L * 2048 * 64);
  k_gemm<1><<<dim3(2, 16, 8), 256, 0, stream>>>(WV, 0, XT_V, 2048L * 256, BV, VW, 256L * 2048);
  k_attn<<<dim3(32, 4, 8), 256, 0, stream>>>(QT, KT, VW, XT_Q);
  k_gemm<2><<<dim3(2, 16, 8), 256, 0, stream>>>(WM, 0, XT_Q, 2048L * 256, b_m, d_out, 256L * 2048);
}

// Round 4
// 110.641 us; speedup vs baseline: 1.3281x; 1.0949x over previous
//
#include <hip/hip_runtime.h>
#include <cstdint>
#include <cstddef>

typedef unsigned short u16;
typedef unsigned int   u32;
typedef __attribute__((ext_vector_type(4))) float f32x4;
typedef __attribute__((ext_vector_type(16))) float f32x16;
typedef __attribute__((ext_vector_type(8))) short bf16x8;
typedef __attribute__((ext_vector_type(4))) unsigned short u16x4;
typedef __attribute__((ext_vector_type(2))) u32 u32x2;
typedef __attribute__((ext_vector_type(4))) u32 u32x4;

#define DEVI static __device__ __forceinline__
#define MFMA16(a,b,c) __builtin_amdgcn_mfma_f32_16x16x32_bf16((a),(b),(c),0,0,0)
#define MFMA32(a,b,c) __builtin_amdgcn_mfma_f32_32x32x16_bf16((a),(b),(c),0,0,0)

DEVI u16 f2b(float f) {
  u32 u = __builtin_bit_cast(u32, f);
  u32 r = u + 0x7fffu + ((u >> 16) & 1u);
  return (u16)(r >> 16);
}

DEVI u32 pkbf(float a, float b) {
  u32 r;
  asm("v_cvt_pk_bf16_f32 %0, %1, %2" : "=v"(r) : "v"(a), "v"(b));
  return r;
}

DEVI void load_lds16(const void* g, void* l) {
  __builtin_amdgcn_global_load_lds(
      (const __attribute__((address_space(1))) u32*)g,
      (__attribute__((address_space(3))) u32*)l, 16, 0, 0);
}

DEVI int perm_o(int o) { return 4 * (o & 63) + (o >> 6); }   // o' = h*64+i -> o = 4i+h

// ---------------------------------------------------------------- weights prep
__global__ __launch_bounds__(256) void k_prep_w(
    const float* __restrict__ wq, const float* __restrict__ wk,
    const float* __restrict__ wv, const float* __restrict__ wm,
    const float* __restrict__ bq, const float* __restrict__ bk, const float* __restrict__ bv,
    u16* __restrict__ WQ, u16* __restrict__ WK, u16* __restrict__ WV, u16* __restrict__ WM,
    float* __restrict__ BQ, float* __restrict__ BK, float* __restrict__ BV)
{
  int row = blockIdx.x, t = threadIdx.x, m = blockIdx.y;
  if (m == 0)      WQ[row * 256 + t] = f2b(wq[perm_o(row) * 256 + t]);
  else if (m == 1) WK[row * 256 + t] = f2b(wk[perm_o(row) * 256 + t]);
  else if (m == 2) WV[row * 256 + t] = f2b(wv[perm_o(row) * 256 + t]);
  else if (m == 3) WM[row * 256 + t] = f2b(wm[row * 256 + perm_o(t)]);
  else if (row == 0) {
    BQ[t] = bq[perm_o(t)];
    BK[t] = bk[perm_o(t)];
    BV[t] = bv[perm_o(t)];
  }
}

// ---------------------------------------------- transpose+convert: [b][c][n]f32 -> [b][n][c]bf16
__global__ __launch_bounds__(256) void k_transpose(
    const float* __restrict__ q, const float* __restrict__ k, const float* __restrict__ v,
    u16* __restrict__ xq, u16* __restrict__ xk, u16* __restrict__ xv)
{
  __shared__ u16 tile[64][68];
  const int N = 2048, D = 256;
  int n0 = blockIdx.x * 64, c0 = blockIdx.y * 64;
  int b = blockIdx.z & 7, which = blockIdx.z >> 3;
  const float* src = (which == 0 ? q : which == 1 ? k : v) + (size_t)b * D * N;
  u16* dst = (which == 0 ? xq : which == 1 ? xk : xv) + (size_t)b * N * D;
  int t = threadIdx.x;
  int cl = t >> 4, ng = t & 15;
#pragma unroll
  for (int cc = 0; cc < 4; ++cc) {
    int c = cl + 16 * cc;
    f32x4 val = *(const f32x4*)&src[(size_t)(c0 + c) * N + n0 + ng * 4];
#pragma unroll
    for (int j = 0; j < 4; ++j) tile[c][ng * 4 + j] = f2b(val[j]);
  }
  __syncthreads();
  int n = t & 63, cq = t >> 6;
  union { u16 s[16]; u32x4 v4[2]; } pk;
#pragma unroll
  for (int j = 0; j < 16; ++j) pk.s[j] = tile[cq * 16 + j][n];
  u32x4* o = (u32x4*)&dst[(size_t)(n0 + n) * D + c0 + cq * 16];
  o[0] = pk.v4[0];
  o[1] = pk.v4[1];
}

// ---------------------------------------------------------------- GEMM 64x64 tile, BK=64
// C = A[M,256] * B[N',256]^T, 4 waves each one 32x32 quadrant (2x2 of 16x16).
// EPI 0: Q/K-proj -> bf16 [b][h][n][i]; EPI 1: V-proj -> bf16 [b][row][col];
// EPI 2: M-proj -> f32 [b][row][col].
template<int EPI>
__global__ __launch_bounds__(256, 4) void k_gemm(
    const u16* __restrict__ A, long sA,
    const u16* __restrict__ Bm, long sB,
    const float* __restrict__ bias,
    void* __restrict__ out, long sOut)
{
  __shared__ u16 lA[64 * 64];
  __shared__ u16 lB[64 * 64];
  int t = threadIdx.x, b = blockIdx.z;
  const u16* Ab = A + (size_t)b * sA + (size_t)blockIdx.x * 64 * 256;
  const u16* Bb = Bm + (size_t)b * sB + (size_t)blockIdx.y * 64 * 256;
  int l = t & 63, w = t >> 6, g = l >> 4, col = l & 15;
  int wr = w >> 1, wc = w & 1;
  f32x4 acc[2][2] = {};
  // staging offsets (hoisted): chunks c = t + 256*j
  u32 sOf[2], sDs[2];
#pragma unroll
  for (int j = 0; j < 2; ++j) {
    int c = t + 256 * j;
    sOf[j] = (u32)(((c >> 3) * 512) + (((c & 7) ^ ((c >> 3) & 7)) << 4));
    sDs[j] = (u32)(c * 16);
  }
  for (int k0 = 0; k0 < 256; k0 += 64) {
    __syncthreads();
#pragma unroll
    for (int j = 0; j < 2; ++j) {
      load_lds16((const char*)(Ab + k0) + sOf[j], (char*)lA + sDs[j]);
      load_lds16((const char*)(Bb + k0) + sOf[j], (char*)lB + sDs[j]);
    }
    asm volatile("s_waitcnt vmcnt(0)" ::: "memory");
    __syncthreads();
#pragma unroll
    for (int kc = 0; kc < 2; ++kc) {
      bf16x8 af[2], bfr[2];
#pragma unroll
      for (int mt = 0; mt < 2; ++mt) {
        int row = wr * 32 + mt * 16 + col;
        af[mt] = *(const bf16x8*)((const char*)lA + row * 128 + (((kc * 4 + g) ^ (row & 7)) << 4));
      }
#pragma unroll
      for (int nt = 0; nt < 2; ++nt) {
        int row = wc * 32 + nt * 16 + col;
        bfr[nt] = *(const bf16x8*)((const char*)lB + row * 128 + (((kc * 4 + g) ^ (row & 7)) << 4));
      }
#pragma unroll
      for (int mt = 0; mt < 2; ++mt)
#pragma unroll
        for (int nt = 0; nt < 2; ++nt)
          acc[mt][nt] = MFMA16(af[mt], bfr[nt], acc[mt][nt]);
    }
  }
  if (EPI == 0) {
    u16* o = (u16*)out + (size_t)b * sOut;
#pragma unroll
    for (int nt = 0; nt < 2; ++nt) {
      int op = blockIdx.y * 64 + wc * 32 + nt * 16 + col;
      int hh = op >> 6, ii = op & 63;
      float bv = bias[op];
#pragma unroll
      for (int mt = 0; mt < 2; ++mt) {
        int nbase = blockIdx.x * 64 + wr * 32 + mt * 16 + g * 4;
#pragma unroll
        for (int r = 0; r < 4; ++r)
          o[((size_t)(hh * 2048 + nbase + r)) * 64 + ii] = f2b(acc[mt][nt][r] + bv);
      }
    }
  } else if (EPI == 1) {
    u16* o = (u16*)out + (size_t)b * sOut;
#pragma unroll
    for (int mt = 0; mt < 2; ++mt)
#pragma unroll
      for (int r = 0; r < 4; ++r) {
        int row = blockIdx.x * 64 + wr * 32 + mt * 16 + g * 4 + r;
        float bv = bias[row];
#pragma unroll
        for (int nt = 0; nt < 2; ++nt) {
          int cn = blockIdx.y * 64 + wc * 32 + nt * 16 + col;
          o[(size_t)row * 2048 + cn] = f2b(acc[mt][nt][r] + bv);
        }
      }
  } else {
    float* o = (float*)out + (size_t)b * sOut;
#pragma unroll
    for (int mt = 0; mt < 2; ++mt)
#pragma unroll
      for (int r = 0; r < 4; ++r) {
        int row = blockIdx.x * 64 + wr * 32 + mt * 16 + g * 4 + r;
        float bv = bias[row];
#pragma unroll
        for (int nt = 0; nt < 2; ++nt) {
          int cn = blockIdx.y * 64 + wc * 32 + nt * 16 + col;
          o[(size_t)row * 2048 + cn] = acc[mt][nt][r] + bv;
        }
      }
  }
}

// ---------------------------------------------------------------- flash attention
// 32x32x16 MFMA, in-register softmax (cvt_pk + permlane32_swap), 2-way KV split
// across wave pairs with LDS combine. Waves: w = (kvh<<1)|qh; each wave 32 q-rows,
// 1024 kv-rows (16 tiles of 64).
__global__ __launch_bounds__(256, 4) void k_attn(
    const u16* __restrict__ Qt, const u16* __restrict__ Kt,
    const u16* __restrict__ Vw, u16* __restrict__ Xws)
{
  __shared__ union {
    u16 stg[2][2][4096];     // [kvh][K|V][64 rows * 64 elems]
    float cmb[2][64][36];    // [qh][lane][32 xacc + psum + m_run]
  } sh;
  const float SC2 = 0.18033688011112042f;  // 0.125 * log2(e)
  int t = threadIdx.x, l = t & 63, w = t >> 6;
  int hi = l >> 5, col = l & 31;
  int qh = w & 1, kvh = w >> 1;
  int nb = blockIdx.x, hh = blockIdx.y, b = blockIdx.z;
  const u16* Qb = Qt + ((size_t)(b * 4 + hh) * 2048) * 64;
  const u16* Kb = Kt + ((size_t)(b * 4 + hh) * 2048) * 64;
  const u16* Vb = Vw + ((size_t)(b * 256 + hh * 64)) * 2048;
  int nq = nb * 64 + qh * 32 + col;

  // Q B-frags: k = ks*16 + hi*8 .. +8 (contiguous bf16)
  bf16x8 qf[4];
#pragma unroll
  for (int ks = 0; ks < 4; ++ks)
    qf[ks] = *(const bf16x8*)&Qb[(size_t)nq * 64 + ks * 16 + hi * 8];

  // hoisted staging offsets: chunks c = tp + 128*j, tp = t&127
  int tp = t & 127;
  u32 kSrc[4], vSrc[4], sDst[4];
#pragma unroll
  for (int j = 0; j < 4; ++j) {
    int c = tp + 128 * j;
    int r = c >> 3, c16 = c & 7;
    kSrc[j] = (u32)((r * 128 + c16 * 16) ^ ((r & 7) << 4));
    vSrc[j] = (u32)(r * 4096 + ((c16 ^ (r & 7)) << 4));
    sDst[j] = (u32)(c * 16);
  }
  // fragment read column offsets: c16 = 2*ks + hi, XOR (col&7)
  u32 offC[4];
#pragma unroll
  for (int ks = 0; ks < 4; ++ks)
    offC[ks] = (u32)(((2 * ks + hi) ^ (col & 7)) << 4);
  const char* kBase0 = (const char*)sh.stg[kvh][0] + col * 128;
  const char* vBase0 = (const char*)sh.stg[kvh][1] + col * 128;

  f32x16 xac[2] = {};
  float psum = 0.0f, m_run = 0.0f;

  for (int it = 0; it < 16; ++it) {
    __syncthreads();
    int tile = kvh * 16 + it;
    const char* kb = (const char*)Kb + (size_t)tile * 8192;
    const char* vb = (const char*)Vb + (size_t)tile * 128;
#pragma unroll
    for (int j = 0; j < 4; ++j)
      load_lds16(kb + kSrc[j], (char*)sh.stg[kvh][0] + sDst[j]);
#pragma unroll
    for (int j = 0; j < 4; ++j)
      load_lds16(vb + vSrc[j], (char*)sh.stg[kvh][1] + sDst[j]);

    // ratchet rescale (rare) — overlaps load latency
    if (__any(psum > 16777216.0f)) {
      const float ds = 5.9604644775390625e-8f;   // 2^-24
      xac[0] *= ds; xac[1] *= ds;
      psum *= ds;
      m_run += 24.0f;
    }
    asm volatile("s_waitcnt vmcnt(0)" ::: "memory");
    __syncthreads();

    // ---- QK^T: S^T[m][n], m-tiles mt=0,1, chain k over d=64 in 4 steps
    f32x16 sac[2] = {};
    __builtin_amdgcn_s_setprio(1);
#pragma unroll
    for (int ks = 0; ks < 4; ++ks) {
      bf16x8 kf0 = *(const bf16x8*)(kBase0 + offC[ks]);
      bf16x8 kf1 = *(const bf16x8*)(kBase0 + 4096 + offC[ks]);
      sac[0] = MFMA32(kf0, qf[ks], sac[0]);
      sac[1] = MFMA32(kf1, qf[ks], sac[1]);
    }
    __builtin_amdgcn_s_setprio(0);

    // ---- softmax (in-register) + P fragments
    bf16x8 pf[4];
#pragma unroll
    for (int mt = 0; mt < 2; ++mt) {
      float p[16];
#pragma unroll
      for (int r = 0; r < 16; ++r) {
        p[r] = __builtin_amdgcn_exp2f(__builtin_fmaf(sac[mt][r], SC2, -m_run));
        psum += p[r];
      }
      u32 A0 = pkbf(p[0],  p[1]),  B0 = pkbf(p[2],  p[3]);
      u32 A1 = pkbf(p[4],  p[5]),  B1 = pkbf(p[6],  p[7]);
      u32 A2 = pkbf(p[8],  p[9]),  B2 = pkbf(p[10], p[11]);
      u32 A3 = pkbf(p[12], p[13]), B3 = pkbf(p[14], p[15]);
      asm("v_permlane32_swap_b32 %0, %1" : "+v"(A0), "+v"(A1));
      asm("v_permlane32_swap_b32 %0, %1" : "+v"(B0), "+v"(B1));
      asm("v_permlane32_swap_b32 %0, %1" : "+v"(A2), "+v"(A3));
      asm("v_permlane32_swap_b32 %0, %1" : "+v"(B2), "+v"(B3));
      union { u32 u[4]; bf16x8 v; } f0, f1;
      f0.u[0] = A0; f0.u[1] = B0; f0.u[2] = A1; f0.u[3] = B1;
      f1.u[0] = A2; f1.u[1] = B2; f1.u[2] = A3; f1.u[3] = B3;
      pf[mt * 2 + 0] = f0.v;
      pf[mt * 2 + 1] = f1.v;
    }

    // ---- PV: x^T[i][n] += V^T[i][m] * P[m][n], chain m in 4 steps
    __builtin_amdgcn_s_setprio(1);
#pragma unroll
    for (int S = 0; S < 4; ++S) {
      bf16x8 vf0 = *(const bf16x8*)(vBase0 + offC[S]);
      bf16x8 vf1 = *(const bf16x8*)(vBase0 + 4096 + offC[S]);
      xac[0] = MFMA32(vf0, pf[S], xac[0]);
      xac[1] = MFMA32(vf1, pf[S], xac[1]);
    }
    __builtin_amdgcn_s_setprio(0);
  }

  // ---- combine kv-halves
  __syncthreads();
  if (kvh == 1) {
    float* d = &sh.cmb[qh][l][0];
#pragma unroll
    for (int r = 0; r < 16; ++r) { d[r] = xac[0][r]; d[16 + r] = xac[1][r]; }
    d[32] = psum; d[33] = m_run;
  }
  __syncthreads();
  if (kvh == 0) {
    const float* s = &sh.cmb[qh][l][0];
    float m1 = s[33], ps1 = s[32];
    float M = fmaxf(m_run, m1);
    float f0 = __builtin_amdgcn_exp2f(m_run - M);
    float f1 = __builtin_amdgcn_exp2f(m1 - M);
    float den = psum * f0 + ps1 * f1;
    den += __shfl_xor(den, 32);
    float inv = 1.0f / den;
    u16* Ob = Xws + (size_t)b * 2048 * 256 + (size_t)nq * 256 + hh * 64;
#pragma unroll
    for (int it2 = 0; it2 < 2; ++it2) {
#pragma unroll
      for (int rq = 0; rq < 4; ++rq) {
        float v0 = (xac[it2][4 * rq + 0] * f0 + s[it2 * 16 + 4 * rq + 0] * f1) * inv;
        float v1 = (xac[it2][4 * rq + 1] * f0 + s[it2 * 16 + 4 * rq + 1] * f1) * inv;
        float v2 = (xac[it2][4 * rq + 2] * f0 + s[it2 * 16 + 4 * rq + 2] * f1) * inv;
        float v3 = (xac[it2][4 * rq + 3] * f0 + s[it2 * 16 + 4 * rq + 3] * f1) * inv;
        u32x2 w2; w2[0] = pkbf(v0, v1); w2[1] = pkbf(v2, v3);
        *(u32x2*)&Ob[it2 * 32 + 8 * rq + 4 * hi] = w2;
      }
    }
  }
}

// ---------------------------------------------------------------- launch
extern "C" void kernel_launch(void* const* d_in, const int* in_sizes, int n_in,
                              void* d_out, int out_size, void* d_ws, size_t ws_size,
                              hipStream_t stream)
{
  const float* q_in = (const float*)d_in[0];
  const float* k_in = (const float*)d_in[1];
  const float* v_in = (const float*)d_in[2];
  const float* w_q  = (const float*)d_in[3];
  const float* b_q  = (const float*)d_in[4];
  const float* w_k  = (const float*)d_in[5];
  const float* b_k  = (const float*)d_in[6];
  const float* w_v  = (const float*)d_in[7];
  const float* b_v  = (const float*)d_in[8];
  const float* w_m  = (const float*)d_in[9];
  const float* b_m  = (const float*)d_in[10];

  char* ws = (char*)d_ws;
  u16* XT_Q = (u16*)(ws + 0);           // [8][2048][256] bf16; reused as attn out
  u16* XT_K = (u16*)(ws + 8388608);
  u16* XT_V = (u16*)(ws + 16777216);
  u16* QT   = (u16*)(ws + 25165824);    // [8][4][2048][64]
  u16* KT   = (u16*)(ws + 33554432);
  u16* VW   = (u16*)(ws + 41943040);    // [8][256][2048]
  u16* WQ   = (u16*)(ws + 50331648);
  u16* WK   = (u16*)(ws + 50462720);
  u16* WV   = (u16*)(ws + 50593792);
  u16* WM   = (u16*)(ws + 50724864);
  float* BQ = (float*)(ws + 50855936);
  float* BK = (float*)(ws + 50856960);
  float* BV = (float*)(ws + 50857984);

  k_prep_w<<<dim3(256, 5), 256, 0, stream>>>(w_q, w_k, w_v, w_m, b_q, b_k, b_v,
                                             WQ, WK, WV, WM, BQ, BK, BV);
  k_transpose<<<dim3(32, 4, 24), 256, 0, stream>>>(q_in, k_in, v_in, XT_Q, XT_K, XT_V);
  k_gemm<0><<<dim3(32, 4, 8), 256, 0, stream>>>(XT_Q, 2048L * 256, WQ, 0, BQ, QT, 4L * 2048 * 64);
  k_gemm<0><<<dim3(32, 4, 8), 256, 0, stream>>>(XT_K, 2048L * 256, WK, 0, BK, KT, 4L * 2048 * 64);
  k_gemm<1><<<dim3(4, 32, 8), 256, 0, stream>>>(WV, 0, XT_V, 2048L * 256, BV, VW, 256L * 2048);
  k_attn<<<dim3(32, 4, 8), 256, 0, stream>>>(QT, KT, VW, XT_Q);
  k_gemm<2><<<dim3(4, 32, 8), 256, 0, stream>>>(WM, 0, XT_Q, 2048L * 256, b_m, d_out, 256L * 2048);
}

// Round 5
// 108.570 us; speedup vs baseline: 1.3534x; 1.0191x over previous
//
#include <hip/hip_runtime.h>
#include <cstdint>
#include <cstddef>

typedef unsigned short u16;
typedef unsigned int   u32;
typedef __attribute__((ext_vector_type(4))) float f32x4;
typedef __attribute__((ext_vector_type(16))) float f32x16;
typedef __attribute__((ext_vector_type(8))) short bf16x8;
typedef __attribute__((ext_vector_type(4))) unsigned short u16x4;
typedef __attribute__((ext_vector_type(2))) u32 u32x2;
typedef __attribute__((ext_vector_type(4))) u32 u32x4;

#define DEVI static __device__ __forceinline__
#define MFMA16(a,b,c) __builtin_amdgcn_mfma_f32_16x16x32_bf16((a),(b),(c),0,0,0)
#define MFMA32(a,b,c) __builtin_amdgcn_mfma_f32_32x32x16_bf16((a),(b),(c),0,0,0)

DEVI u16 f2b(float f) {
  u32 u = __builtin_bit_cast(u32, f);
  u32 r = u + 0x7fffu + ((u >> 16) & 1u);
  return (u16)(r >> 16);
}

DEVI u32 pkbf(float a, float b) {
  u32 r;
  asm("v_cvt_pk_bf16_f32 %0, %1, %2" : "=v"(r) : "v"(a), "v"(b));
  return r;
}

DEVI void load_lds16(const void* g, void* l) {
  __builtin_amdgcn_global_load_lds(
      (const __attribute__((address_space(1))) u32*)g,
      (__attribute__((address_space(3))) u32*)l, 16, 0, 0);
}

DEVI int perm_o(int o) { return 4 * (o & 63) + (o >> 6); }   // o' = h*64+i -> o = 4i+h

// ---------------------------------------------------------------- weights prep
__global__ __launch_bounds__(256) void k_prep_w(
    const float* __restrict__ wq, const float* __restrict__ wk,
    const float* __restrict__ wv, const float* __restrict__ wm,
    const float* __restrict__ bq, const float* __restrict__ bk, const float* __restrict__ bv,
    u16* __restrict__ WQ, u16* __restrict__ WK, u16* __restrict__ WV, u16* __restrict__ WM,
    float* __restrict__ BQ, float* __restrict__ BK, float* __restrict__ BV)
{
  int row = blockIdx.x, t = threadIdx.x, m = blockIdx.y;
  if (m == 0)      WQ[row * 256 + t] = f2b(wq[perm_o(row) * 256 + t]);
  else if (m == 1) WK[row * 256 + t] = f2b(wk[perm_o(row) * 256 + t]);
  else if (m == 2) WV[row * 256 + t] = f2b(wv[perm_o(row) * 256 + t]);
  else if (m == 3) WM[row * 256 + t] = f2b(wm[row * 256 + perm_o(t)]);
  else if (row == 0) {
    BQ[t] = bq[perm_o(t)];
    BK[t] = bk[perm_o(t)];
    BV[t] = bv[perm_o(t)];
  }
}

// ---------------------------------------------- transpose+convert: [b][c][n]f32 -> [b][n][c]bf16
__global__ __launch_bounds__(256) void k_transpose(
    const float* __restrict__ q, const float* __restrict__ k, const float* __restrict__ v,
    u16* __restrict__ xq, u16* __restrict__ xk, u16* __restrict__ xv)
{
  __shared__ u16 tile[64][68];
  const int N = 2048, D = 256;
  int n0 = blockIdx.x * 64, c0 = blockIdx.y * 64;
  int b = blockIdx.z & 7, which = blockIdx.z >> 3;
  const float* src = (which == 0 ? q : which == 1 ? k : v) + (size_t)b * D * N;
  u16* dst = (which == 0 ? xq : which == 1 ? xk : xv) + (size_t)b * N * D;
  int t = threadIdx.x;
  int cl = t >> 4, ng = t & 15;
#pragma unroll
  for (int cc = 0; cc < 4; ++cc) {
    int c = cl + 16 * cc;
    f32x4 val = *(const f32x4*)&src[(size_t)(c0 + c) * N + n0 + ng * 4];
#pragma unroll
    for (int j = 0; j < 4; ++j) tile[c][ng * 4 + j] = f2b(val[j]);
  }
  __syncthreads();
  int n = t & 63, cq = t >> 6;
  union { u16 s[16]; u32x4 v4[2]; } pk;
#pragma unroll
  for (int j = 0; j < 16; ++j) pk.s[j] = tile[cq * 16 + j][n];
  u32x4* o = (u32x4*)&dst[(size_t)(n0 + n) * D + c0 + cq * 16];
  o[0] = pk.v4[0];
  o[1] = pk.v4[1];
}

// ---------------------------------------------------------------- GEMM 64x64 tile, BK=64
// Double-buffered staging with counted vmcnt (never 0 mid-loop).
template<int EPI>
__global__ __launch_bounds__(256, 4) void k_gemm(
    const u16* __restrict__ A, long sA,
    const u16* __restrict__ Bm, long sB,
    const float* __restrict__ bias,
    void* __restrict__ out, long sOut)
{
  __shared__ u16 lA[2][64 * 64];
  __shared__ u16 lB[2][64 * 64];
  int t = threadIdx.x, b = blockIdx.z;
  const u16* Ab = A + (size_t)b * sA + (size_t)blockIdx.x * 64 * 256;
  const u16* Bb = Bm + (size_t)b * sB + (size_t)blockIdx.y * 64 * 256;
  int l = t & 63, w = t >> 6, g = l >> 4, col = l & 15;
  int wr = w >> 1, wc = w & 1;
  f32x4 acc[2][2] = {};
  u32 sOf[2], sDs[2];
#pragma unroll
  for (int j = 0; j < 2; ++j) {
    int ci = t + 256 * j;
    int r = ci >> 3, c = ci & 7;
    sOf[j] = (u32)(r * 512 + ((c ^ (r & 7)) << 4));
    sDs[j] = (u32)(ci * 16);
  }
  auto stage = [&](int buf, int k0) {
#pragma unroll
    for (int j = 0; j < 2; ++j) {
      load_lds16((const char*)Ab + k0 * 2 + sOf[j], (char*)lA[buf] + sDs[j]);
      load_lds16((const char*)Bb + k0 * 2 + sOf[j], (char*)lB[buf] + sDs[j]);
    }
  };
  stage(0, 0);
  for (int s = 0; s < 4; ++s) {
    int cur = s & 1;
    if (s < 3) {
      stage(cur ^ 1, (s + 1) * 64);
      asm volatile("s_waitcnt vmcnt(4)" ::: "memory");
    } else {
      asm volatile("s_waitcnt vmcnt(0)" ::: "memory");
    }
    __syncthreads();
#pragma unroll
    for (int kc = 0; kc < 2; ++kc) {
      bf16x8 af[2], bfr[2];
#pragma unroll
      for (int mt = 0; mt < 2; ++mt) {
        int row = wr * 32 + mt * 16 + col;
        af[mt] = *(const bf16x8*)((const char*)lA[cur] + row * 128 + (((kc * 4 + g) ^ (row & 7)) << 4));
      }
#pragma unroll
      for (int nt = 0; nt < 2; ++nt) {
        int row = wc * 32 + nt * 16 + col;
        bfr[nt] = *(const bf16x8*)((const char*)lB[cur] + row * 128 + (((kc * 4 + g) ^ (row & 7)) << 4));
      }
#pragma unroll
      for (int mt = 0; mt < 2; ++mt)
#pragma unroll
        for (int nt = 0; nt < 2; ++nt)
          acc[mt][nt] = MFMA16(af[mt], bfr[nt], acc[mt][nt]);
    }
    __syncthreads();
  }
  if (EPI == 0) {
    u16* o = (u16*)out + (size_t)b * sOut;
#pragma unroll
    for (int nt = 0; nt < 2; ++nt) {
      int op = blockIdx.y * 64 + wc * 32 + nt * 16 + col;
      int hh = op >> 6, ii = op & 63;
      float bv = bias[op];
#pragma unroll
      for (int mt = 0; mt < 2; ++mt) {
        int nbase = blockIdx.x * 64 + wr * 32 + mt * 16 + g * 4;
#pragma unroll
        for (int r = 0; r < 4; ++r)
          o[((size_t)(hh * 2048 + nbase + r)) * 64 + ii] = f2b(acc[mt][nt][r] + bv);
      }
    }
  } else if (EPI == 1) {
    u16* o = (u16*)out + (size_t)b * sOut;
#pragma unroll
    for (int mt = 0; mt < 2; ++mt)
#pragma unroll
      for (int r = 0; r < 4; ++r) {
        int row = blockIdx.x * 64 + wr * 32 + mt * 16 + g * 4 + r;
        float bv = bias[row];
#pragma unroll
        for (int nt = 0; nt < 2; ++nt) {
          int cn = blockIdx.y * 64 + wc * 32 + nt * 16 + col;
          o[(size_t)row * 2048 + cn] = f2b(acc[mt][nt][r] + bv);
        }
      }
  } else {
    float* o = (float*)out + (size_t)b * sOut;
#pragma unroll
    for (int mt = 0; mt < 2; ++mt)
#pragma unroll
      for (int r = 0; r < 4; ++r) {
        int row = blockIdx.x * 64 + wr * 32 + mt * 16 + g * 4 + r;
        float bv = bias[row];
#pragma unroll
        for (int nt = 0; nt < 2; ++nt) {
          int cn = blockIdx.y * 64 + wc * 32 + nt * 16 + col;
          o[(size_t)row * 2048 + cn] = acc[mt][nt][r] + bv;
        }
      }
  }
}

// ---------------------------------------------------------------- flash attention
// 4 waves x 32 q-rows = 128 q/block, full KV sweep (no split), 32 tiles of 64.
// Double-buffered K/V (LDS 32KB), counted vmcnt(4), conflict-free (r>>2)
// XOR swizzle, in-register softmax (streaming max-free + ratchet).
__global__ __launch_bounds__(256, 2) void k_attn(
    const u16* __restrict__ Qt, const u16* __restrict__ Kt,
    const u16* __restrict__ Vw, u16* __restrict__ Xws)
{
  __shared__ u16 stg[2][2][4096];    // [buf][K|V][64 rows * 64]
  const float SC2 = 0.18033688011112042f;  // 0.125 * log2(e)
  int t = threadIdx.x, l = t & 63, w = t >> 6;
  int hi = l >> 5, col = l & 31;
  int nb = blockIdx.x, hh = blockIdx.y, b = blockIdx.z;
  const u16* Qb = Qt + ((size_t)(b * 4 + hh) * 2048) * 64;
  const u16* Kb = Kt + ((size_t)(b * 4 + hh) * 2048) * 64;
  const u16* Vb = Vw + ((size_t)(b * 256 + hh * 64)) * 2048;
  int nq = nb * 128 + w * 32 + col;

  bf16x8 qf[4];
#pragma unroll
  for (int ks = 0; ks < 4; ++ks)
    qf[ks] = *(const bf16x8*)&Qb[(size_t)nq * 64 + ks * 16 + hi * 8];

  // staging: 512 chunks of 16B per tile per matrix; thread does chunks t, t+256
  u32 kSrc[2], vSrc[2], sDst[2];
#pragma unroll
  for (int j = 0; j < 2; ++j) {
    int ci = t + 256 * j;
    int r = ci >> 3, c = ci & 7;
    u32 sw = (u32)((c ^ ((r >> 2) & 7)) << 4);
    kSrc[j] = (u32)(r * 128) + sw;
    vSrc[j] = (u32)(r * 4096) + sw;
    sDst[j] = (u32)(ci * 16);
  }
  // fragment read chunk offsets: chunk (2ks+hi) XOR ((row>>2)&7); row=col (+32 same swz)
  u32 offC[4];
#pragma unroll
  for (int ks = 0; ks < 4; ++ks)
    offC[ks] = (u32)(((2 * ks + hi) ^ ((col >> 2) & 7)) << 4);

  f32x16 xac0 = {}, xac1 = {};
  float psum = 0.0f, m_run = 0.0f;

  auto stage = [&](int buf, int tile) {
    const char* kb = (const char*)Kb + (size_t)tile * 8192;
    const char* vb = (const char*)Vb + (size_t)tile * 128;
#pragma unroll
    for (int j = 0; j < 2; ++j)
      load_lds16(kb + kSrc[j], (char*)stg[buf][0] + sDst[j]);
#pragma unroll
    for (int j = 0; j < 2; ++j)
      load_lds16(vb + vSrc[j], (char*)stg[buf][1] + sDst[j]);
  };

  stage(0, 0);
  for (int it = 0; it < 32; ++it) {
    int cur = it & 1;
    if (it < 31) {
      stage(cur ^ 1, it + 1);
      // ratchet rescale (rare) — overlaps in-flight loads
      if (__any(psum > 16777216.0f)) {
        const float ds = 5.9604644775390625e-8f;   // 2^-24
        xac0 *= ds; xac1 *= ds;
        psum *= ds;
        m_run += 24.0f;
      }
      asm volatile("s_waitcnt vmcnt(4)" ::: "memory");
    } else {
      asm volatile("s_waitcnt vmcnt(0)" ::: "memory");
    }
    __syncthreads();
    const char* kK = (const char*)stg[cur][0] + col * 128;
    const char* kV = (const char*)stg[cur][1] + col * 128;

    // ---- QK^T: S^T[m][n]
    f32x16 sac0 = {}, sac1 = {};
    __builtin_amdgcn_s_setprio(1);
#pragma unroll
    for (int ks = 0; ks < 4; ++ks) {
      bf16x8 kf0 = *(const bf16x8*)(kK + offC[ks]);
      bf16x8 kf1 = *(const bf16x8*)(kK + 4096 + offC[ks]);
      sac0 = MFMA32(kf0, qf[ks], sac0);
      sac1 = MFMA32(kf1, qf[ks], sac1);
    }
    __builtin_amdgcn_s_setprio(0);

    // ---- softmax (in-register, streaming) + P fragments
    bf16x8 pf[4];
#pragma unroll
    for (int mt = 0; mt < 2; ++mt) {
      const f32x16& sc = mt ? sac1 : sac0;
      float p[16];
#pragma unroll
      for (int r = 0; r < 16; ++r) {
        p[r] = __builtin_amdgcn_exp2f(__builtin_fmaf(sc[r], SC2, -m_run));
        psum += p[r];
      }
      u32 A0 = pkbf(p[0],  p[1]),  B0 = pkbf(p[2],  p[3]);
      u32 A1 = pkbf(p[4],  p[5]),  B1 = pkbf(p[6],  p[7]);
      u32 A2 = pkbf(p[8],  p[9]),  B2 = pkbf(p[10], p[11]);
      u32 A3 = pkbf(p[12], p[13]), B3 = pkbf(p[14], p[15]);
      asm("v_permlane32_swap_b32 %0, %1" : "+v"(A0), "+v"(A1));
      asm("v_permlane32_swap_b32 %0, %1" : "+v"(B0), "+v"(B1));
      asm("v_permlane32_swap_b32 %0, %1" : "+v"(A2), "+v"(A3));
      asm("v_permlane32_swap_b32 %0, %1" : "+v"(B2), "+v"(B3));
      union { u32 u[4]; bf16x8 v; } f0, f1;
      f0.u[0] = A0; f0.u[1] = B0; f0.u[2] = A1; f0.u[3] = B1;
      f1.u[0] = A2; f1.u[1] = B2; f1.u[2] = A3; f1.u[3] = B3;
      pf[mt * 2 + 0] = f0.v;
      pf[mt * 2 + 1] = f1.v;
    }

    // ---- PV: x^T[i][n] += V^T[i][m] * P[m][n]
    __builtin_amdgcn_s_setprio(1);
#pragma unroll
    for (int S = 0; S < 4; ++S) {
      bf16x8 vf0 = *(const bf16x8*)(kV + offC[S]);
      bf16x8 vf1 = *(const bf16x8*)(kV + 4096 + offC[S]);
      xac0 = MFMA32(vf0, pf[S], xac0);
      xac1 = MFMA32(vf1, pf[S], xac1);
    }
    __builtin_amdgcn_s_setprio(0);
    __syncthreads();
  }

  psum += __shfl_xor(psum, 32);
  float inv = 1.0f / psum;
  u16* Ob = Xws + (size_t)b * 2048 * 256 + (size_t)nq * 256 + hh * 64;
#pragma unroll
  for (int it2 = 0; it2 < 2; ++it2) {
    const f32x16& xa = it2 ? xac1 : xac0;
#pragma unroll
    for (int rq = 0; rq < 4; ++rq) {
      float v0 = xa[4 * rq + 0] * inv;
      float v1 = xa[4 * rq + 1] * inv;
      float v2 = xa[4 * rq + 2] * inv;
      float v3 = xa[4 * rq + 3] * inv;
      u32x2 w2; w2[0] = pkbf(v0, v1); w2[1] = pkbf(v2, v3);
      *(u32x2*)&Ob[it2 * 32 + 8 * rq + 4 * hi] = w2;
    }
  }
}

// ---------------------------------------------------------------- launch
extern "C" void kernel_launch(void* const* d_in, const int* in_sizes, int n_in,
                              void* d_out, int out_size, void* d_ws, size_t ws_size,
                              hipStream_t stream)
{
  const float* q_in = (const float*)d_in[0];
  const float* k_in = (const float*)d_in[1];
  const float* v_in = (const float*)d_in[2];
  const float* w_q  = (const float*)d_in[3];
  const float* b_q  = (const float*)d_in[4];
  const float* w_k  = (const float*)d_in[5];
  const float* b_k  = (const float*)d_in[6];
  const float* w_v  = (const float*)d_in[7];
  const float* b_v  = (const float*)d_in[8];
  const float* w_m  = (const float*)d_in[9];
  const float* b_m  = (const float*)d_in[10];

  char* ws = (char*)d_ws;
  u16* XT_Q = (u16*)(ws + 0);           // [8][2048][256] bf16; reused as attn out
  u16* XT_K = (u16*)(ws + 8388608);
  u16* XT_V = (u16*)(ws + 16777216);
  u16* QT   = (u16*)(ws + 25165824);    // [8][4][2048][64]
  u16* KT   = (u16*)(ws + 33554432);
  u16* VW   = (u16*)(ws + 41943040);    // [8][256][2048]
  u16* WQ   = (u16*)(ws + 50331648);
  u16* WK   = (u16*)(ws + 50462720);
  u16* WV   = (u16*)(ws + 50593792);
  u16* WM   = (u16*)(ws + 50724864);
  float* BQ = (float*)(ws + 50855936);
  float* BK = (float*)(ws + 50856960);
  float* BV = (float*)(ws + 50857984);

  k_prep_w<<<dim3(256, 5), 256, 0, stream>>>(w_q, w_k, w_v, w_m, b_q, b_k, b_v,
                                             WQ, WK, WV, WM, BQ, BK, BV);
  k_transpose<<<dim3(32, 4, 24), 256, 0, stream>>>(q_in, k_in, v_in, XT_Q, XT_K, XT_V);
  k_gemm<0><<<dim3(32, 4, 8), 256, 0, stream>>>(XT_Q, 2048L * 256, WQ, 0, BQ, QT, 4L * 2048 * 64);
  k_gemm<0><<<dim3(32, 4, 8), 256, 0, stream>>>(XT_K, 2048L * 256, WK, 0, BK, KT, 4L * 2048 * 64);
  k_gemm<1><<<dim3(4, 32, 8), 256, 0, stream>>>(WV, 0, XT_V, 2048L * 256, BV, VW, 256L * 2048);
  k_attn<<<dim3(16, 4, 8), 256, 0, stream>>>(QT, KT, VW, XT_Q);
  k_gemm<2><<<dim3(4, 32, 8), 256, 0, stream>>>(WM, 0, XT_Q, 2048L * 256, b_m, d_out, 256L * 2048);
}

// Round 6
// 105.939 us; speedup vs baseline: 1.3870x; 1.0248x over previous
//
#include <hip/hip_runtime.h>
#include <cstdint>
#include <cstddef>

typedef unsigned short u16;
typedef unsigned int   u32;
typedef __attribute__((ext_vector_type(4))) float f32x4;
typedef __attribute__((ext_vector_type(16))) float f32x16;
typedef __attribute__((ext_vector_type(8))) short bf16x8;
typedef __attribute__((ext_vector_type(4))) unsigned short u16x4;
typedef __attribute__((ext_vector_type(2))) u32 u32x2;
typedef __attribute__((ext_vector_type(4))) u32 u32x4;

#define DEVI static __device__ __forceinline__
#define MFMA16(a,b,c) __builtin_amdgcn_mfma_f32_16x16x32_bf16((a),(b),(c),0,0,0)
#define MFMA32(a,b,c) __builtin_amdgcn_mfma_f32_32x32x16_bf16((a),(b),(c),0,0,0)
#define BAR()   __builtin_amdgcn_s_barrier()
#define CFENCE() asm volatile("" ::: "memory")

DEVI u16 f2b(float f) {
  u32 u = __builtin_bit_cast(u32, f);
  u32 r = u + 0x7fffu + ((u >> 16) & 1u);
  return (u16)(r >> 16);
}

DEVI u32 pkbf(float a, float b) {
  u32 r;
  asm("v_cvt_pk_bf16_f32 %0, %1, %2" : "=v"(r) : "v"(a), "v"(b));
  return r;
}

DEVI void load_lds16(const void* g, void* l) {
  __builtin_amdgcn_global_load_lds(
      (const __attribute__((address_space(1))) u32*)g,
      (__attribute__((address_space(3))) u32*)l, 16, 0, 0);
}

DEVI int perm_o(int o) { return 4 * (o & 63) + (o >> 6); }   // o' = h*64+i -> o = 4i+h

// ---------------------------------------------------------------- weights prep
__global__ __launch_bounds__(256) void k_prep_w(
    const float* __restrict__ wq, const float* __restrict__ wk,
    const float* __restrict__ wv, const float* __restrict__ wm,
    const float* __restrict__ bq, const float* __restrict__ bk, const float* __restrict__ bv,
    u16* __restrict__ WQ, u16* __restrict__ WK, u16* __restrict__ WV, u16* __restrict__ WM,
    float* __restrict__ BQ, float* __restrict__ BK, float* __restrict__ BV)
{
  int row = blockIdx.x, t = threadIdx.x, m = blockIdx.y;
  if (m == 0)      WQ[row * 256 + t] = f2b(wq[perm_o(row) * 256 + t]);
  else if (m == 1) WK[row * 256 + t] = f2b(wk[perm_o(row) * 256 + t]);
  else if (m == 2) WV[row * 256 + t] = f2b(wv[perm_o(row) * 256 + t]);
  else if (m == 3) WM[row * 256 + t] = f2b(wm[row * 256 + perm_o(t)]);
  else if (row == 0) {
    BQ[t] = bq[perm_o(t)];
    BK[t] = bk[perm_o(t)];
    BV[t] = bv[perm_o(t)];
  }
}

// ---------------------------------------------- transpose+convert: [b][c][n]f32 -> [b][n][c]bf16
__global__ __launch_bounds__(256) void k_transpose(
    const float* __restrict__ q, const float* __restrict__ k, const float* __restrict__ v,
    u16* __restrict__ xq, u16* __restrict__ xk, u16* __restrict__ xv)
{
  __shared__ u16 tile[64][68];
  const int N = 2048, D = 256;
  int n0 = blockIdx.x * 64, c0 = blockIdx.y * 64;
  int b = blockIdx.z & 7, which = blockIdx.z >> 3;
  const float* src = (which == 0 ? q : which == 1 ? k : v) + (size_t)b * D * N;
  u16* dst = (which == 0 ? xq : which == 1 ? xk : xv) + (size_t)b * N * D;
  int t = threadIdx.x;
  int cl = t >> 4, ng = t & 15;
#pragma unroll
  for (int cc = 0; cc < 4; ++cc) {
    int c = cl + 16 * cc;
    f32x4 val = *(const f32x4*)&src[(size_t)(c0 + c) * N + n0 + ng * 4];
#pragma unroll
    for (int j = 0; j < 4; ++j) tile[c][ng * 4 + j] = f2b(val[j]);
  }
  __syncthreads();
  int n = t & 63, cq = t >> 6;
  union { u16 s[16]; u32x4 v4[2]; } pk;
#pragma unroll
  for (int j = 0; j < 16; ++j) pk.s[j] = tile[cq * 16 + j][n];
  u32x4* o = (u32x4*)&dst[(size_t)(n0 + n) * D + c0 + cq * 16];
  o[0] = pk.v4[0];
  o[1] = pk.v4[1];
}

// ---------------------------------------------------------------- GEMM 64x64 tile, BK=64
// Double-buffered staging; counted vmcnt + RAW s_barrier (no implicit vmcnt(0) drain).
template<int EPI>
__global__ __launch_bounds__(256, 4) void k_gemm(
    const u16* __restrict__ A, long sA,
    const u16* __restrict__ Bm, long sB,
    const float* __restrict__ bias,
    void* __restrict__ out, long sOut)
{
  __shared__ u16 lA[2][64 * 64];
  __shared__ u16 lB[2][64 * 64];
  int t = threadIdx.x, b = blockIdx.z;
  const u16* Ab = A + (size_t)b * sA + (size_t)blockIdx.x * 64 * 256;
  const u16* Bb = Bm + (size_t)b * sB + (size_t)blockIdx.y * 64 * 256;
  int l = t & 63, w = t >> 6, g = l >> 4, col = l & 15;
  int wr = w >> 1, wc = w & 1;
  f32x4 acc[2][2] = {};
  u32 sOf[2], sDs[2];
#pragma unroll
  for (int j = 0; j < 2; ++j) {
    int ci = t + 256 * j;
    int r = ci >> 3, c = ci & 7;
    sOf[j] = (u32)(r * 512 + ((c ^ (r & 7)) << 4));
    sDs[j] = (u32)(ci * 16);
  }
  auto stage = [&](int buf, int k0) {
#pragma unroll
    for (int j = 0; j < 2; ++j) {
      load_lds16((const char*)Ab + k0 * 2 + sOf[j], (char*)lA[buf] + sDs[j]);
      load_lds16((const char*)Bb + k0 * 2 + sOf[j], (char*)lB[buf] + sDs[j]);
    }
  };
  stage(0, 0);
  for (int s = 0; s < 4; ++s) {
    int cur = s & 1;
    if (s < 3) {
      stage(cur ^ 1, (s + 1) * 64);
      asm volatile("s_waitcnt vmcnt(4)" ::: "memory");
    } else {
      asm volatile("s_waitcnt vmcnt(0)" ::: "memory");
    }
    BAR(); CFENCE();
#pragma unroll
    for (int kc = 0; kc < 2; ++kc) {
      bf16x8 af[2], bfr[2];
#pragma unroll
      for (int mt = 0; mt < 2; ++mt) {
        int row = wr * 32 + mt * 16 + col;
        af[mt] = *(const bf16x8*)((const char*)lA[cur] + row * 128 + (((kc * 4 + g) ^ (row & 7)) << 4));
      }
#pragma unroll
      for (int nt = 0; nt < 2; ++nt) {
        int row = wc * 32 + nt * 16 + col;
        bfr[nt] = *(const bf16x8*)((const char*)lB[cur] + row * 128 + (((kc * 4 + g) ^ (row & 7)) << 4));
      }
#pragma unroll
      for (int mt = 0; mt < 2; ++mt)
#pragma unroll
        for (int nt = 0; nt < 2; ++nt)
          acc[mt][nt] = MFMA16(af[mt], bfr[nt], acc[mt][nt]);
    }
    if (s < 3) { CFENCE(); BAR(); }
  }
  if (EPI == 0) {
    u16* o = (u16*)out + (size_t)b * sOut;
#pragma unroll
    for (int nt = 0; nt < 2; ++nt) {
      int op = blockIdx.y * 64 + wc * 32 + nt * 16 + col;
      int hh = op >> 6, ii = op & 63;
      float bv = bias[op];
#pragma unroll
      for (int mt = 0; mt < 2; ++mt) {
        int nbase = blockIdx.x * 64 + wr * 32 + mt * 16 + g * 4;
#pragma unroll
        for (int r = 0; r < 4; ++r)
          o[((size_t)(hh * 2048 + nbase + r)) * 64 + ii] = f2b(acc[mt][nt][r] + bv);
      }
    }
  } else if (EPI == 1) {
    u16* o = (u16*)out + (size_t)b * sOut;
#pragma unroll
    for (int mt = 0; mt < 2; ++mt)
#pragma unroll
      for (int r = 0; r < 4; ++r) {
        int row = blockIdx.x * 64 + wr * 32 + mt * 16 + g * 4 + r;
        float bv = bias[row];
#pragma unroll
        for (int nt = 0; nt < 2; ++nt) {
          int cn = blockIdx.y * 64 + wc * 32 + nt * 16 + col;
          o[(size_t)row * 2048 + cn] = f2b(acc[mt][nt][r] + bv);
        }
      }
  } else {
    float* o = (float*)out + (size_t)b * sOut;
#pragma unroll
    for (int mt = 0; mt < 2; ++mt)
#pragma unroll
      for (int r = 0; r < 4; ++r) {
        int row = blockIdx.x * 64 + wr * 32 + mt * 16 + g * 4 + r;
        float bv = bias[row];
#pragma unroll
        for (int nt = 0; nt < 2; ++nt) {
          int cn = blockIdx.y * 64 + wc * 32 + nt * 16 + col;
          o[(size_t)row * 2048 + cn] = acc[mt][nt][r] + bv;
        }
      }
  }
}

// ---------------------------------------------------------------- flash attention
// 4 waves x 32 q-rows = 128 q/block, full KV sweep, 32 tiles of 64.
// Double-buffered K/V, counted vmcnt(4) + RAW s_barrier — prefetch stays in
// flight across barriers (T3/T4). In-register streaming softmax.
__global__ __launch_bounds__(256, 2) void k_attn(
    const u16* __restrict__ Qt, const u16* __restrict__ Kt,
    const u16* __restrict__ Vw, u16* __restrict__ Xws)
{
  __shared__ u16 stg[2][2][4096];    // [buf][K|V][64 rows * 64]
  const float SC2 = 0.18033688011112042f;  // 0.125 * log2(e)
  int t = threadIdx.x, l = t & 63;
  int w = t >> 6;
  int hi = l >> 5, col = l & 31;
  int nb = blockIdx.x, hh = blockIdx.y, b = blockIdx.z;
  const u16* Qb = Qt + ((size_t)(b * 4 + hh) * 2048) * 64;
  const u16* Kb = Kt + ((size_t)(b * 4 + hh) * 2048) * 64;
  const u16* Vb = Vw + ((size_t)(b * 256 + hh * 64)) * 2048;
  int nq = nb * 128 + w * 32 + col;

  bf16x8 qf[4];
#pragma unroll
  for (int ks = 0; ks < 4; ++ks)
    qf[ks] = *(const bf16x8*)&Qb[(size_t)nq * 64 + ks * 16 + hi * 8];

  u32 kSrc[2], vSrc[2], sDst[2];
#pragma unroll
  for (int j = 0; j < 2; ++j) {
    int ci = t + 256 * j;
    int r = ci >> 3, c = ci & 7;
    u32 sw = (u32)((c ^ ((r >> 2) & 7)) << 4);
    kSrc[j] = (u32)(r * 128) + sw;
    vSrc[j] = (u32)(r * 4096) + sw;
    sDst[j] = (u32)(ci * 16);
  }
  u32 offC[4];
#pragma unroll
  for (int ks = 0; ks < 4; ++ks)
    offC[ks] = (u32)(((2 * ks + hi) ^ ((col >> 2) & 7)) << 4);

  f32x16 xac0 = {}, xac1 = {};
  float psum = 0.0f, m_run = 0.0f;

  auto stage = [&](int buf, int tile) {
    const char* kb = (const char*)Kb + (size_t)tile * 8192;
    const char* vb = (const char*)Vb + (size_t)tile * 128;
#pragma unroll
    for (int j = 0; j < 2; ++j)
      load_lds16(kb + kSrc[j], (char*)stg[buf][0] + sDst[j]);
#pragma unroll
    for (int j = 0; j < 2; ++j)
      load_lds16(vb + vSrc[j], (char*)stg[buf][1] + sDst[j]);
  };

  stage(0, 0);
  for (int it = 0; it < 32; ++it) {
    int cur = it & 1;
    if (it < 31) {
      stage(cur ^ 1, it + 1);
      // ratchet rescale (rare) — overlaps in-flight loads
      if (__any(psum > 16777216.0f)) {
        const float ds = 5.9604644775390625e-8f;   // 2^-24
        xac0 *= ds; xac1 *= ds;
        psum *= ds;
        m_run += 24.0f;
      }
      asm volatile("s_waitcnt vmcnt(4)" ::: "memory");   // own cur-tile loads done
    } else {
      asm volatile("s_waitcnt vmcnt(0)" ::: "memory");
    }
    BAR(); CFENCE();                                     // raw barrier: no vmcnt(0) drain
    const char* kK = (const char*)stg[cur][0] + col * 128;
    const char* kV = (const char*)stg[cur][1] + col * 128;

    // ---- QK^T: S^T[m][n]
    f32x16 sac0 = {}, sac1 = {};
    __builtin_amdgcn_s_setprio(1);
#pragma unroll
    for (int ks = 0; ks < 4; ++ks) {
      bf16x8 kf0 = *(const bf16x8*)(kK + offC[ks]);
      bf16x8 kf1 = *(const bf16x8*)(kK + 4096 + offC[ks]);
      sac0 = MFMA32(kf0, qf[ks], sac0);
      sac1 = MFMA32(kf1, qf[ks], sac1);
    }
    __builtin_amdgcn_s_setprio(0);

    // ---- softmax (in-register, streaming) + P fragments
    bf16x8 pf[4];
#pragma unroll
    for (int mt = 0; mt < 2; ++mt) {
      const f32x16& sc = mt ? sac1 : sac0;
      float p[16];
#pragma unroll
      for (int r = 0; r < 16; ++r) {
        p[r] = __builtin_amdgcn_exp2f(__builtin_fmaf(sc[r], SC2, -m_run));
        psum += p[r];
      }
      u32 A0 = pkbf(p[0],  p[1]),  B0 = pkbf(p[2],  p[3]);
      u32 A1 = pkbf(p[4],  p[5]),  B1 = pkbf(p[6],  p[7]);
      u32 A2 = pkbf(p[8],  p[9]),  B2 = pkbf(p[10], p[11]);
      u32 A3 = pkbf(p[12], p[13]), B3 = pkbf(p[14], p[15]);
      asm("v_permlane32_swap_b32 %0, %1" : "+v"(A0), "+v"(A1));
      asm("v_permlane32_swap_b32 %0, %1" : "+v"(B0), "+v"(B1));
      asm("v_permlane32_swap_b32 %0, %1" : "+v"(A2), "+v"(A3));
      asm("v_permlane32_swap_b32 %0, %1" : "+v"(B2), "+v"(B3));
      union { u32 u[4]; bf16x8 v; } f0, f1;
      f0.u[0] = A0; f0.u[1] = B0; f0.u[2] = A1; f0.u[3] = B1;
      f1.u[0] = A2; f1.u[1] = B2; f1.u[2] = A3; f1.u[3] = B3;
      pf[mt * 2 + 0] = f0.v;
      pf[mt * 2 + 1] = f1.v;
    }

    // ---- PV: x^T[i][n] += V^T[i][m] * P[m][n]
    __builtin_amdgcn_s_setprio(1);
#pragma unroll
    for (int S = 0; S < 4; ++S) {
      bf16x8 vf0 = *(const bf16x8*)(kV + offC[S]);
      bf16x8 vf1 = *(const bf16x8*)(kV + 4096 + offC[S]);
      xac0 = MFMA32(vf0, pf[S], xac0);
      xac1 = MFMA32(vf1, pf[S], xac1);
    }
    __builtin_amdgcn_s_setprio(0);
    if (it < 31) { CFENCE(); BAR(); }   // protect buf from next iter's overwrite
  }

  psum += __shfl_xor(psum, 32);
  float inv = 1.0f / psum;
  u16* Ob = Xws + (size_t)b * 2048 * 256 + (size_t)nq * 256 + hh * 64;
#pragma unroll
  for (int it2 = 0; it2 < 2; ++it2) {
    const f32x16& xa = it2 ? xac1 : xac0;
#pragma unroll
    for (int rq = 0; rq < 4; ++rq) {
      float v0 = xa[4 * rq + 0] * inv;
      float v1 = xa[4 * rq + 1] * inv;
      float v2 = xa[4 * rq + 2] * inv;
      float v3 = xa[4 * rq + 3] * inv;
      u32x2 w2; w2[0] = pkbf(v0, v1); w2[1] = pkbf(v2, v3);
      *(u32x2*)&Ob[it2 * 32 + 8 * rq + 4 * hi] = w2;
    }
  }
}

// ---------------------------------------------------------------- launch
extern "C" void kernel_launch(void* const* d_in, const int* in_sizes, int n_in,
                              void* d_out, int out_size, void* d_ws, size_t ws_size,
                              hipStream_t stream)
{
  const float* q_in = (const float*)d_in[0];
  const float* k_in = (const float*)d_in[1];
  const float* v_in = (const float*)d_in[2];
  const float* w_q  = (const float*)d_in[3];
  const float* b_q  = (const float*)d_in[4];
  const float* w_k  = (const float*)d_in[5];
  const float* b_k  = (const float*)d_in[6];
  const float* w_v  = (const float*)d_in[7];
  const float* b_v  = (const float*)d_in[8];
  const float* w_m  = (const float*)d_in[9];
  const float* b_m  = (const float*)d_in[10];

  char* ws = (char*)d_ws;
  u16* XT_Q = (u16*)(ws + 0);           // [8][2048][256] bf16; reused as attn out
  u16* XT_K = (u16*)(ws + 8388608);
  u16* XT_V = (u16*)(ws + 16777216);
  u16* QT   = (u16*)(ws + 25165824);    // [8][4][2048][64]
  u16* KT   = (u16*)(ws + 33554432);
  u16* VW   = (u16*)(ws + 41943040);    // [8][256][2048]
  u16* WQ   = (u16*)(ws + 50331648);
  u16* WK   = (u16*)(ws + 50462720);
  u16* WV   = (u16*)(ws + 50593792);
  u16* WM   = (u16*)(ws + 50724864);
  float* BQ = (float*)(ws + 50855936);
  float* BK = (float*)(ws + 50856960);
  float* BV = (float*)(ws + 50857984);

  k_prep_w<<<dim3(256, 5), 256, 0, stream>>>(w_q, w_k, w_v, w_m, b_q, b_k, b_v,
                                             WQ, WK, WV, WM, BQ, BK, BV);
  k_transpose<<<dim3(32, 4, 24), 256, 0, stream>>>(q_in, k_in, v_in, XT_Q, XT_K, XT_V);
  k_gemm<0><<<dim3(32, 4, 8), 256, 0, stream>>>(XT_Q, 2048L * 256, WQ, 0, BQ, QT, 4L * 2048 * 64);
  k_gemm<0><<<dim3(32, 4, 8), 256, 0, stream>>>(XT_K, 2048L * 256, WK, 0, BK, KT, 4L * 2048 * 64);
  k_gemm<1><<<dim3(4, 32, 8), 256, 0, stream>>>(WV, 0, XT_V, 2048L * 256, BV, VW, 256L * 2048);
  k_attn<<<dim3(16, 4, 8), 256, 0, stream>>>(QT, KT, VW, XT_Q);
  k_gemm<2><<<dim3(4, 32, 8), 256, 0, stream>>>(WM, 0, XT_Q, 2048L * 256, b_m, d_out, 256L * 2048);
}